// Round 8
// baseline (1243.417 us; speedup 1.0000x reference)
//
#include <hip/hip_runtime.h>
#include <cstddef>

#define NROWS 16384
#define NE    8192
#define DD    256

typedef unsigned long long u64;
typedef float vf4 __attribute__((ext_vector_type(4)));
typedef short bf16x8 __attribute__((ext_vector_type(8)));
typedef float f32x4 __attribute__((ext_vector_type(4)));
typedef unsigned short us8 __attribute__((ext_vector_type(8)));

#define OH_TOT ((size_t)NROWS * NE)           // 134217728 floats
#define OH_VEC ((OH_TOT - 4) / 4)             // 33554431 aligned vf4 slots
#define CAND_CAP 4000000
#define LLIST_CAP 2048

// ---------------------------------------------------------------------------
// k_rowsq: zsq/esq in numpy pairwise order (bit-exact). For emb rows, ALSO
// writes the bf16 copy eb[8192][256] (RNE) used by the screen's direct-from-
// global B loads. wadd = rigorous screen window (round-6/7-validated):
//   2*( (zsq+2)*1.2e-7  +  2*(1e-6*Ssum)  + 5e-8 )
// Inits best[], counts, cand_n.
// ---------------------------------------------------------------------------
__global__ __launch_bounds__(256) void k_rowsq(
    const float* __restrict__ z, const float* __restrict__ emb,
    float* __restrict__ zsq, float* __restrict__ esq,
    u64* __restrict__ best, int* __restrict__ counts,
    float* __restrict__ wadd, int* __restrict__ cand_n,
    unsigned short* __restrict__ eb)
{
  const int g = blockIdx.x * 256 + threadIdx.x;   // 0 .. 24575
  if (g == 0) *cand_n = 0;
  if (g < NE) counts[g] = 0;
  if (g < NROWS) best[g] = ~0ull;

  const float* row;
  float* outp;
  if (g < NROWS) { row = z + (size_t)g * DD;            outp = zsq + g; }
  else           { row = emb + (size_t)(g - NROWS) * DD; outp = esq + (g - NROWS); }

  float sa = 0.0f;
  float half_s[2];
#pragma unroll
  for (int h = 0; h < 2; ++h) {
    const float* p = row + h * 128;
    float r[8];
    {
      const float4 v0 = *(const float4*)(p);
      const float4 v1 = *(const float4*)(p + 4);
      const float xs[8] = {v0.x, v0.y, v0.z, v0.w, v1.x, v1.y, v1.z, v1.w};
#pragma unroll
      for (int j = 0; j < 8; ++j) {
        float sq = xs[j] * xs[j];
        asm volatile("" : "+v"(sq));   // np rounds x*x before the add chain
        r[j] = sq;
        sa += fabsf(xs[j]);
      }
    }
    for (int i = 8; i < 128; i += 8) {
      const float4 v0 = *(const float4*)(p + i);
      const float4 v1 = *(const float4*)(p + i + 4);
      const float xs[8] = {v0.x, v0.y, v0.z, v0.w, v1.x, v1.y, v1.z, v1.w};
#pragma unroll
      for (int j = 0; j < 8; ++j) {
        float sq = xs[j] * xs[j];
        asm volatile("" : "+v"(sq));
        r[j] = r[j] + sq;
        sa += fabsf(xs[j]);
      }
    }
    half_s[h] = ((r[0] + r[1]) + (r[2] + r[3])) + ((r[4] + r[5]) + (r[6] + r[7]));
  }
  const float zs = half_s[0] + half_s[1];
  *outp = zs;
  if (g < NROWS) {
    wadd[g] = 2.0f * ((zs + 2.0f) * 1.2e-7f + 2.0f * (1.0e-6f * sa) + 5.0e-8f);
  } else {
    // bf16 copy of this emb row (RNE)
    unsigned short* er = eb + (size_t)(g - NROWS) * DD;
#pragma unroll 4
    for (int c = 0; c < DD; c += 8) {
      const float4 v0 = *(const float4*)(row + c);
      const float4 v1 = *(const float4*)(row + c + 4);
      us8 u;
      const float xs[8] = {v0.x, v0.y, v0.z, v0.w, v1.x, v1.y, v1.z, v1.w};
#pragma unroll
      for (int j = 0; j < 8; ++j) {
        const unsigned b = __float_as_uint(xs[j]);
        u[j] = (unsigned short)((b + 0x7FFFu + ((b >> 16) & 1u)) >> 16);
      }
      *(us8*)(er + c) = u;
    }
  }
}

__device__ __forceinline__ unsigned short f2bf_rne(float f) {
  const unsigned u = __float_as_uint(f);
  return (unsigned short)((u + 0x7FFFu + ((u >> 16) & 1u)) >> 16);
}
__device__ __forceinline__ unsigned encf(float f) {
  const unsigned u = __float_as_uint(f);
  return (u & 0x80000000u) ? ~u : (u | 0x80000000u);
}
__device__ __forceinline__ float decf(unsigned k) {
  const unsigned u = (k & 0x80000000u) ? (k ^ 0x80000000u) : ~k;
  return __uint_as_float(u);
}

// ---------------------------------------------------------------------------
// k_screen v2 (barrier-free main loop):
//   1024 blocks x 256 thr; block = 64 rows x 2048 cols. XCD-aware decode:
//   XCD pair handles one col-quarter -> its 1 MB eb slice is L2-resident.
//   A-frags (z) persistent in regs (32 VGPR/wave: 16 rows). B-frags loaded
//   DIRECTLY from the bf16 eb in global (L2-hit; 16x64B lines per wave-load)
//   -- no LDS staging, no in-loop barriers, no in-loop f2bf.
//   Per 32-col step: 16 MFMA + margin test vs per-row threshold; rare slow
//   path pushes candidates to an LDS list. Running min via barrier-free LDS
//   atomicMin (stale smin => looser thr => superset: still exact).
//   Steps 0-1 skip emission (thr cold) and are re-screened after the sweep
//   with the final threshold. One-hot zero-fill fused (2 stores/step).
// ---------------------------------------------------------------------------
__global__ __launch_bounds__(256) void k_screen(
    const float* __restrict__ z, const unsigned short* __restrict__ eb,
    const float* __restrict__ esq, const float* __restrict__ wadd,
    unsigned* __restrict__ cand, int* __restrict__ cand_n,
    float* __restrict__ ohbase)
{
  __shared__ unsigned smin[64];
  __shared__ float wl[64];
  __shared__ unsigned llist[LLIST_CAP];
  __shared__ unsigned lcnt;
  __shared__ unsigned gbase;

  const int tid = threadIdx.x;
  const int b = blockIdx.x;                 // 0..1023
  const int x = b & 7;                      // default XCD round-robin id
  const int quarter = x >> 1;               // 2 XCDs per col-quarter
  const int panel = (b >> 3) * 2 + (x & 1); // 0..255, bijective
  const int R0 = panel * 64;
  const int C0 = quarter * 2048;

  const int wave = tid >> 6;                // 0..3: rows wave*16..+15
  const int lane = tid & 63;
  const int l15 = lane & 15;
  const int kg = lane >> 4;                 // 0..3

  if (tid < 64) { smin[tid] = 0xFFFFFFFFu; wl[tid] = wadd[R0 + tid]; }
  if (tid == 0) lcnt = 0;

  // one-hot zero-fill state: block owns 32768 vf4 slots
  float* zp0 = ohbase + 2;
  size_t zt = (size_t)b * 32768 + tid;
  const vf4 zzero = {0.0f, 0.0f, 0.0f, 0.0f};
  if (b == 0 && tid == 0) { ohbase[0] = 0.0f; ohbase[1] = 0.0f; }
  if (b == 1023 && tid == 0) { ohbase[OH_TOT - 2] = 0.0f; ohbase[OH_TOT - 1] = 0.0f; }

  // persistent A-frags: row R0 + wave*16 + l15, k = kt*32 + kg*8
  bf16x8 af[8];
  {
    const float* zp_ = z + (size_t)(R0 + wave * 16 + l15) * DD + kg * 8;
#pragma unroll
    for (int kt = 0; kt < 8; ++kt) {
      const float4 a0 = *(const float4*)(zp_ + kt * 32);
      const float4 a1 = *(const float4*)(zp_ + kt * 32 + 4);
      bf16x8 w;
      w[0] = (short)f2bf_rne(a0.x); w[1] = (short)f2bf_rne(a0.y);
      w[2] = (short)f2bf_rne(a0.z); w[3] = (short)f2bf_rne(a0.w);
      w[4] = (short)f2bf_rne(a1.x); w[5] = (short)f2bf_rne(a1.y);
      w[6] = (short)f2bf_rne(a1.z); w[7] = (short)f2bf_rne(a1.w);
      af[kt] = w;
    }
  }
  __syncthreads();

  // this lane's output rows (C/D mapping: row = kg*4+r, col = l15)
  const int rbase = wave * 16 + kg * 4;     // + r
  float wlr[4], thr[4], rm[4];
#pragma unroll
  for (int r = 0; r < 4; ++r) { wlr[r] = wl[rbase + r]; thr[r] = 1e30f; rm[r] = 1e30f; }

#define PUSH(E_)                                                            \
  {                                                                         \
    const unsigned s_ = atomicAdd(&lcnt, 1u);                               \
    if (s_ < LLIST_CAP) llist[s_] = (E_);                                   \
    else { const int g_ = atomicAdd(cand_n, 1);                             \
           if (g_ < CAND_CAP) cand[g_] = (E_); }                            \
  }

#define STEPBODY(S_, EMIT_, DOZ_)                                           \
  {                                                                         \
    const int c0 = C0 + (S_) * 32 + l15;                                    \
    const int c1 = c0 + 16;                                                 \
    const bf16x8* bp0 = (const bf16x8*)(eb + (size_t)c0 * DD) + kg;         \
    const bf16x8* bp1 = (const bf16x8*)(eb + (size_t)c1 * DD) + kg;         \
    f32x4 a0 = (f32x4){0.0f, 0.0f, 0.0f, 0.0f};                             \
    f32x4 a1 = (f32x4){0.0f, 0.0f, 0.0f, 0.0f};                             \
    _Pragma("unroll")                                                       \
    for (int kt = 0; kt < 8; ++kt) {                                        \
      a0 = __builtin_amdgcn_mfma_f32_16x16x32_bf16(af[kt], bp0[kt * 4], a0, 0, 0, 0); \
      a1 = __builtin_amdgcn_mfma_f32_16x16x32_bf16(af[kt], bp1[kt * 4], a1, 0, 0, 0); \
    }                                                                       \
    if (DOZ_) {                                                             \
      if (zt < OH_VEC) __builtin_nontemporal_store(zzero, (vf4*)(zp0 + 4 * zt)); \
      zt += 256;                                                            \
      if (zt < OH_VEC) __builtin_nontemporal_store(zzero, (vf4*)(zp0 + 4 * zt)); \
      zt += 256;                                                            \
    }                                                                       \
    const float ev0 = esq[c0];                                              \
    const float ev1 = esq[c1];                                              \
    float rv0[4], rv1[4];                                                   \
    float gm = 1e30f;                                                       \
    _Pragma("unroll")                                                       \
    for (int r = 0; r < 4; ++r) {                                           \
      rv0[r] = ev0 - 2.0f * a0[r];                                          \
      rv1[r] = ev1 - 2.0f * a1[r];                                          \
      const float mn = fminf(rv0[r], rv1[r]);                               \
      rm[r] = fminf(rm[r], mn);                                             \
      gm = fminf(gm, mn - thr[r]);                                          \
    }                                                                       \
    if ((EMIT_) && gm <= 0.0f) {                                            \
      _Pragma("unroll")                                                     \
      for (int r = 0; r < 4; ++r) {                                         \
        if (rv0[r] <= thr[r]) PUSH(((unsigned)(R0 + rbase + r) << 13) | (unsigned)c0); \
        if (rv1[r] <= thr[r]) PUSH(((unsigned)(R0 + rbase + r) << 13) | (unsigned)c1); \
      }                                                                     \
    }                                                                       \
  }

#define FLUSH_REFRESH                                                       \
  {                                                                         \
    _Pragma("unroll")                                                       \
    for (int r = 0; r < 4; ++r) {                                           \
      float mn = rm[r];                                                     \
      mn = fminf(mn, __shfl_xor(mn, 1, 16));                                \
      mn = fminf(mn, __shfl_xor(mn, 2, 16));                                \
      mn = fminf(mn, __shfl_xor(mn, 4, 16));                                \
      mn = fminf(mn, __shfl_xor(mn, 8, 16));                                \
      if (l15 == 0) atomicMin(&smin[rbase + r], encf(mn));                  \
    }                                                                       \
    _Pragma("unroll")                                                       \
    for (int r = 0; r < 4; ++r) thr[r] = decf(smin[rbase + r]) + wlr[r];    \
  }

  for (int s = 0; s < 64; ++s) {
    STEPBODY(s, (s >= 2), 1);
    if (s == 1 || (s & 7) == 7) FLUSH_REFRESH;
  }

  __syncthreads();                 // all waves' smin final
#pragma unroll
  for (int r = 0; r < 4; ++r) thr[r] = decf(smin[rbase + r]) + wlr[r];
  // re-screen the cold steps 0,1 with the final threshold
  STEPBODY(0, 1, 0);
  STEPBODY(1, 1, 0);

  __syncthreads();
  const unsigned n = (lcnt < LLIST_CAP) ? lcnt : LLIST_CAP;
  if (tid == 0) gbase = (unsigned)atomicAdd(cand_n, (int)n);
  __syncthreads();
  for (unsigned i = tid; i < n; i += 256) {
    const unsigned g = gbase + i;
    if (g < CAND_CAP) cand[g] = llist[i];
  }
}

// ---------------------------------------------------------------------------
// k_recheck: exact fp32 chain (ascending-k fmaf, identical rounding to the
// reference) per candidate; u64-packed atomicMin -> exact argmin with
// np.argmin first-index tie-break.
// ---------------------------------------------------------------------------
__global__ __launch_bounds__(256) void k_recheck(
    const float* __restrict__ z, const float* __restrict__ emb,
    const float* __restrict__ zsq, const float* __restrict__ esq,
    const unsigned* __restrict__ cand, const int* __restrict__ cand_n,
    u64* __restrict__ best)
{
  const int n = min(*cand_n, CAND_CAP);
  for (int i = blockIdx.x * 256 + threadIdx.x; i < n; i += gridDim.x * 256) {
    const unsigned e = cand[i];
    const int row = (int)(e >> 13);
    const int col = (int)(e & (NE - 1));
    const float4* zr = (const float4*)(z + (size_t)row * DD);
    const float4* er = (const float4*)(emb + (size_t)col * DD);
    float dot = 0.0f;
#pragma unroll 8
    for (int q = 0; q < 64; ++q) {
      const float4 a = zr[q];
      const float4 b = er[q];
      dot = fmaf(a.x, b.x, dot);
      dot = fmaf(a.y, b.y, dot);
      dot = fmaf(a.z, b.z, dot);
      dot = fmaf(a.w, b.w, dot);
    }
    const float s1 = zsq[row] + esq[col];
    const float dv = s1 - 2.0f * dot;
    atomicMin(&best[row], ((u64)__float_as_uint(dv) << 32) | (unsigned)col);
  }
}

// ---------------------------------------------------------------------------
// k_gather2: 4 rows per block. z_q gather, one-hot 1.0 scatter (zeros laid
// down by k_screen), float(index), counts, per-block loss partial.
// ---------------------------------------------------------------------------
__global__ __launch_bounds__(256) void k_gather2(
    const float* __restrict__ z, const float* __restrict__ emb,
    const u64* __restrict__ best,
    float* __restrict__ out_zq, float* __restrict__ out_onehot,
    float* __restrict__ out_idx, float* __restrict__ partials,
    int* __restrict__ counts)
{
  __shared__ float sred[256];
  const int row = blockIdx.x * 4 + (threadIdx.x >> 6);
  const int lane = threadIdx.x & 63;
  const int idx = (int)(unsigned)(best[row] & 0xffffffffull);
  const int k0 = lane * 4;

  const float4 e  = *(const float4*)(emb + (size_t)idx * DD + k0);
  const float4 zv = *(const float4*)(z + (size_t)row * DD + k0);
  *(float4*)(out_zq + (size_t)row * DD + k0) = e;

  const float dx = e.x - zv.x, dy = e.y - zv.y, dz = e.z - zv.z, dw = e.w - zv.w;
  sred[threadIdx.x] = dx * dx + dy * dy + dz * dz + dw * dw;

  if (lane == 0) {
    out_idx[row] = (float)idx;
    out_onehot[(size_t)row * NE + idx] = 1.0f;
    atomicAdd(&counts[idx], 1);
  }
  __syncthreads();
  for (int s = 128; s > 0; s >>= 1) {
    if (threadIdx.x < s) sred[threadIdx.x] += sred[threadIdx.x + s];
    __syncthreads();
  }
  if (threadIdx.x == 0) partials[blockIdx.x] = sred[0];
}

// ---------------------------------------------------------------------------
// k_final: loss = 1.25 * sum(partials) / (N*D); perplexity from counts.
// ---------------------------------------------------------------------------
__global__ __launch_bounds__(256) void k_final(
    const int* __restrict__ counts, const float* __restrict__ partials,
    float* __restrict__ out_loss, float* __restrict__ out_perp)
{
  __shared__ float sred[256];
  __shared__ float sl[256];
  float le = 0.0f;
  for (int e = threadIdx.x; e < NE; e += 256) {
    const float p = (float)counts[e] * (1.0f / 16384.0f);
    le += p * logf(p + 1e-10f);
  }
  float ll = 0.0f;
  for (int b = threadIdx.x; b < NROWS / 4; b += 256) ll += partials[b];
  sred[threadIdx.x] = le;
  sl[threadIdx.x] = ll;
  __syncthreads();
  for (int s = 128; s > 0; s >>= 1) {
    if (threadIdx.x < s) {
      sred[threadIdx.x] += sred[threadIdx.x + s];
      sl[threadIdx.x] += sl[threadIdx.x + s];
    }
    __syncthreads();
  }
  if (threadIdx.x == 0) {
    *out_perp = expf(-sred[0]);
    *out_loss = sl[0] * (1.25f / 4194304.0f);  // (1+beta) * sum / (N*D)
  }
}

// ---------------------------------------------------------------------------
// Output layout (float32, reference return order):
//   [0] loss | [1..4194304] z_q_st | [4194305] perplexity
//   [4194306..] one-hot | [138412034..] indices (as float)
// Workspace layout (floats): zsq 16K | esq 8K | best 32K | counts 8K |
//   partials 4K | wadd 16K | cand_n+pad | eb (bf16, 1M floats) | cand (16MB)
// (bulk intermediates live in d_ws -- d_out reads are uncached/slow.)
// ---------------------------------------------------------------------------
extern "C" void kernel_launch(void* const* d_in, const int* in_sizes, int n_in,
                              void* d_out, int out_size, void* d_ws, size_t ws_size,
                              hipStream_t stream) {
  const float* z   = (const float*)d_in[0];
  const float* emb = (const float*)d_in[1];

  float* out        = (float*)d_out;
  float* out_loss   = out;
  float* out_zq     = out + 1;
  float* out_perp   = out + 4194305;
  float* out_onehot = out + 4194306;
  float* out_idx    = out + 138412034;

  float* zsq      = (float*)d_ws;            // 16384 f
  float* esq      = zsq + NROWS;             // 8192 f
  u64*   best     = (u64*)(esq + NE);        // 16384 u64
  int*   counts   = (int*)(best + NROWS);    // 8192 int
  float* partials = (float*)(counts + NE);   // 4096 f
  float* wadd     = partials + 4096;         // 16384 f
  int*   cand_n   = (int*)(wadd + NROWS);    // 1 int (+pad to 16B)
  unsigned short* eb = (unsigned short*)(wadd + NROWS + 4);   // 8192*256 bf16
  unsigned* cand  = (unsigned*)(eb + (size_t)NE * DD);        // 4M u32

  k_rowsq<<<96, 256, 0, stream>>>(z, emb, zsq, esq, best, counts, wadd, cand_n, eb);
  k_screen<<<1024, 256, 0, stream>>>(z, eb, esq, wadd, cand, cand_n, out_onehot);
  k_recheck<<<512, 256, 0, stream>>>(z, emb, zsq, esq, cand, cand_n, best);
  k_gather2<<<NROWS / 4, 256, 0, stream>>>(z, emb, best, out_zq, out_onehot,
                                           out_idx, partials, counts);
  k_final<<<1, 256, 0, stream>>>(counts, partials, out_loss, out_perp);
}

// Round 9
// 1013.277 us; speedup vs baseline: 1.2271x; 1.2271x over previous
//
#include <hip/hip_runtime.h>
#include <cstddef>

#define NROWS 16384
#define NE    8192
#define DD    256

typedef unsigned long long u64;
typedef float vf4 __attribute__((ext_vector_type(4)));
typedef short bf16x8 __attribute__((ext_vector_type(8)));
typedef float f32x4 __attribute__((ext_vector_type(4)));
typedef unsigned short us8 __attribute__((ext_vector_type(8)));

#define OH_TOT ((size_t)NROWS * NE)           // 134217728 floats
#define OH_VEC ((OH_TOT - 4) / 4)             // 33554431 aligned vf4 slots
#define CAND_CAP 4000000
#define LLIST_CAP 2048

// ---------------------------------------------------------------------------
// k_rowsq: zsq/esq in numpy pairwise order (bit-exact). For emb rows, ALSO
// writes ebf: the bf16 copy of emb in MFMA-FRAGMENT-MAJOR order so the
// screen's B-loads are fully coalesced:
//   fragment slot (tile*8 + kt)*64 + lane, lane = kg*16 + (col&15),
//   holds eb[col][kt*32 + kg*8 .. +7]   (tile = col>>4)
// wadd = rigorous screen window (round-6/7/8-validated):
//   2*( (zsq+2)*1.2e-7 + 2*(1e-6*Ssum) + 5e-8 )
// Inits best[], counts, cand_n.
// ---------------------------------------------------------------------------
__global__ __launch_bounds__(256) void k_rowsq(
    const float* __restrict__ z, const float* __restrict__ emb,
    float* __restrict__ zsq, float* __restrict__ esq,
    u64* __restrict__ best, int* __restrict__ counts,
    float* __restrict__ wadd, int* __restrict__ cand_n,
    unsigned short* __restrict__ ebf)
{
  const int g = blockIdx.x * 256 + threadIdx.x;   // 0 .. 24575
  if (g == 0) *cand_n = 0;
  if (g < NE) counts[g] = 0;
  if (g < NROWS) best[g] = ~0ull;

  const float* row;
  float* outp;
  if (g < NROWS) { row = z + (size_t)g * DD;            outp = zsq + g; }
  else           { row = emb + (size_t)(g - NROWS) * DD; outp = esq + (g - NROWS); }

  float sa = 0.0f;
  float half_s[2];
#pragma unroll
  for (int h = 0; h < 2; ++h) {
    const float* p = row + h * 128;
    float r[8];
    {
      const float4 v0 = *(const float4*)(p);
      const float4 v1 = *(const float4*)(p + 4);
      const float xs[8] = {v0.x, v0.y, v0.z, v0.w, v1.x, v1.y, v1.z, v1.w};
#pragma unroll
      for (int j = 0; j < 8; ++j) {
        float sq = xs[j] * xs[j];
        asm volatile("" : "+v"(sq));   // np rounds x*x before the add chain
        r[j] = sq;
        sa += fabsf(xs[j]);
      }
    }
    for (int i = 8; i < 128; i += 8) {
      const float4 v0 = *(const float4*)(p + i);
      const float4 v1 = *(const float4*)(p + i + 4);
      const float xs[8] = {v0.x, v0.y, v0.z, v0.w, v1.x, v1.y, v1.z, v1.w};
#pragma unroll
      for (int j = 0; j < 8; ++j) {
        float sq = xs[j] * xs[j];
        asm volatile("" : "+v"(sq));
        r[j] = r[j] + sq;
        sa += fabsf(xs[j]);
      }
    }
    half_s[h] = ((r[0] + r[1]) + (r[2] + r[3])) + ((r[4] + r[5]) + (r[6] + r[7]));
  }
  const float zs = half_s[0] + half_s[1];
  *outp = zs;
  if (g < NROWS) {
    wadd[g] = 2.0f * ((zs + 2.0f) * 1.2e-7f + 2.0f * (1.0e-6f * sa) + 5.0e-8f);
  } else {
    const int c = g - NROWS;
    const int t = c >> 4, l = c & 15;
#pragma unroll
    for (int kt = 0; kt < 8; ++kt) {
#pragma unroll
      for (int kq = 0; kq < 4; ++kq) {
        const float4 v0 = *(const float4*)(row + kt * 32 + kq * 8);
        const float4 v1 = *(const float4*)(row + kt * 32 + kq * 8 + 4);
        const float xs[8] = {v0.x, v0.y, v0.z, v0.w, v1.x, v1.y, v1.z, v1.w};
        us8 u;
#pragma unroll
        for (int j = 0; j < 8; ++j) {
          const unsigned b = __float_as_uint(xs[j]);
          u[j] = (unsigned short)((b + 0x7FFFu + ((b >> 16) & 1u)) >> 16);
        }
        *(us8*)(ebf + (((size_t)(t * 8 + kt)) * 64 + kq * 16 + l) * 8) = u;
      }
    }
  }
}

__device__ __forceinline__ unsigned short f2bf_rne(float f) {
  const unsigned u = __float_as_uint(f);
  return (unsigned short)((u + 0x7FFFu + ((u >> 16) & 1u)) >> 16);
}
__device__ __forceinline__ unsigned encf(float f) {
  const unsigned u = __float_as_uint(f);
  return (u & 0x80000000u) ? ~u : (u | 0x80000000u);
}
__device__ __forceinline__ float decf(unsigned k) {
  const unsigned u = (k & 0x80000000u) ? (k ^ 0x80000000u) : ~k;
  return __uint_as_float(u);
}

// ---------------------------------------------------------------------------
// k_screen v3: barrier-free MFMA screen.
//   1024 blocks x 256 thr (4 blocks/CU); block = 64 rows x 2048 cols.
//   A-frags persistent in regs; B-frags via COALESCED 1-KB wave-loads from
//   fragment-major ebf (no LDS, no gather). Per 32-col step: 16 loads,
//   16 MFMAs in 4 independent chains (even/odd kt partials, summed at the
//   end -- extra fp32 add <= |dot|*6e-8, absorbed by the window slack).
//   Running min via barrier-free LDS atomicMin (stale => looser => superset).
//   Steps 0-1 re-screened at the end with the final threshold.
//   One-hot zero-fill moved to an END burst so NT stores never sit in the
//   vmcnt queue between a B-load and its dependent wait (round-8 lesson).
// ---------------------------------------------------------------------------
__global__ __launch_bounds__(256) void k_screen(
    const float* __restrict__ z, const unsigned short* __restrict__ ebf,
    const float* __restrict__ esq, const float* __restrict__ wadd,
    unsigned* __restrict__ cand, int* __restrict__ cand_n,
    float* __restrict__ ohbase)
{
  __shared__ unsigned smin[64];
  __shared__ float wl[64];
  __shared__ unsigned llist[LLIST_CAP];
  __shared__ unsigned lcnt;
  __shared__ unsigned gbase;

  const int tid = threadIdx.x;
  const int b = blockIdx.x;                 // 0..1023
  const int x = b & 7;                      // XCD round-robin id
  const int quarter = x >> 1;               // 2 XCDs per col-quarter
  const int panel = (b >> 3) * 2 + (x & 1); // 0..255, bijective
  const int R0 = panel * 64;
  const int C0 = quarter * 2048;
  const int T0 = C0 >> 4;                   // first 16-col tile

  const int wave = tid >> 6;                // rows wave*16..+15
  const int lane = tid & 63;
  const int l15 = lane & 15;
  const int kg = lane >> 4;

  if (tid < 64) { smin[tid] = 0xFFFFFFFFu; wl[tid] = wadd[R0 + tid]; }
  if (tid == 0) lcnt = 0;

  // persistent A-frags: row R0 + wave*16 + l15, k = kt*32 + kg*8
  bf16x8 af[8];
  {
    const float* zp_ = z + (size_t)(R0 + wave * 16 + l15) * DD + kg * 8;
#pragma unroll
    for (int kt = 0; kt < 8; ++kt) {
      const float4 a0 = *(const float4*)(zp_ + kt * 32);
      const float4 a1 = *(const float4*)(zp_ + kt * 32 + 4);
      bf16x8 w;
      w[0] = (short)f2bf_rne(a0.x); w[1] = (short)f2bf_rne(a0.y);
      w[2] = (short)f2bf_rne(a0.z); w[3] = (short)f2bf_rne(a0.w);
      w[4] = (short)f2bf_rne(a1.x); w[5] = (short)f2bf_rne(a1.y);
      w[6] = (short)f2bf_rne(a1.z); w[7] = (short)f2bf_rne(a1.w);
      af[kt] = w;
    }
  }
  __syncthreads();

  const int rbase = wave * 16 + kg * 4;     // + r  (C/D: row=kg*4+r, col=l15)
  float wlr[4], thr[4], rm[4];
#pragma unroll
  for (int r = 0; r < 4; ++r) { wlr[r] = wl[rbase + r]; thr[r] = 1e30f; rm[r] = 1e30f; }

#define PUSH(E_)                                                            \
  {                                                                         \
    const unsigned s_ = atomicAdd(&lcnt, 1u);                               \
    if (s_ < LLIST_CAP) llist[s_] = (E_);                                   \
    else { const int g_ = atomicAdd(cand_n, 1);                             \
           if (g_ < CAND_CAP) cand[g_] = (E_); }                            \
  }

#define STEPBODY(S_, EMIT_)                                                 \
  {                                                                         \
    const int t0 = T0 + 2 * (S_);                                           \
    const bf16x8* fb = (const bf16x8*)ebf;                                  \
    bf16x8 b0[8], b1[8];                                                    \
    _Pragma("unroll")                                                       \
    for (int kt = 0; kt < 8; ++kt) {                                        \
      b0[kt] = fb[(size_t)(t0 * 8 + kt) * 64 + lane];                       \
      b1[kt] = fb[(size_t)((t0 + 1) * 8 + kt) * 64 + lane];                 \
    }                                                                       \
    f32x4 e0 = (f32x4){0,0,0,0}, o0 = (f32x4){0,0,0,0};                     \
    f32x4 e1 = (f32x4){0,0,0,0}, o1 = (f32x4){0,0,0,0};                     \
    _Pragma("unroll")                                                       \
    for (int kt = 0; kt < 8; kt += 2) {                                     \
      e0 = __builtin_amdgcn_mfma_f32_16x16x32_bf16(af[kt], b0[kt], e0, 0, 0, 0);         \
      o0 = __builtin_amdgcn_mfma_f32_16x16x32_bf16(af[kt + 1], b0[kt + 1], o0, 0, 0, 0); \
      e1 = __builtin_amdgcn_mfma_f32_16x16x32_bf16(af[kt], b1[kt], e1, 0, 0, 0);         \
      o1 = __builtin_amdgcn_mfma_f32_16x16x32_bf16(af[kt + 1], b1[kt + 1], o1, 0, 0, 0); \
    }                                                                       \
    const int c0 = C0 + (S_) * 32 + l15;                                    \
    const int c1 = c0 + 16;                                                 \
    const float ev0 = esq[c0];                                              \
    const float ev1 = esq[c1];                                              \
    float rv0[4], rv1[4];                                                   \
    float gm = 1e30f;                                                       \
    _Pragma("unroll")                                                       \
    for (int r = 0; r < 4; ++r) {                                           \
      rv0[r] = ev0 - 2.0f * (e0[r] + o0[r]);                                \
      rv1[r] = ev1 - 2.0f * (e1[r] + o1[r]);                                \
      const float mn = fminf(rv0[r], rv1[r]);                               \
      rm[r] = fminf(rm[r], mn);                                             \
      gm = fminf(gm, mn - thr[r]);                                          \
    }                                                                       \
    if ((EMIT_) && gm <= 0.0f) {                                            \
      _Pragma("unroll")                                                     \
      for (int r = 0; r < 4; ++r) {                                         \
        if (rv0[r] <= thr[r]) PUSH(((unsigned)(R0 + rbase + r) << 13) | (unsigned)c0); \
        if (rv1[r] <= thr[r]) PUSH(((unsigned)(R0 + rbase + r) << 13) | (unsigned)c1); \
      }                                                                     \
    }                                                                       \
  }

#define FLUSH_REFRESH                                                       \
  {                                                                         \
    _Pragma("unroll")                                                       \
    for (int r = 0; r < 4; ++r) {                                           \
      float mn = rm[r];                                                     \
      mn = fminf(mn, __shfl_xor(mn, 1, 16));                                \
      mn = fminf(mn, __shfl_xor(mn, 2, 16));                                \
      mn = fminf(mn, __shfl_xor(mn, 4, 16));                                \
      mn = fminf(mn, __shfl_xor(mn, 8, 16));                                \
      if (l15 == 0) atomicMin(&smin[rbase + r], encf(mn));                  \
    }                                                                       \
    _Pragma("unroll")                                                       \
    for (int r = 0; r < 4; ++r) thr[r] = decf(smin[rbase + r]) + wlr[r];    \
  }

#pragma unroll 1
  for (int s = 0; s < 64; ++s) {
    STEPBODY(s, (s >= 2));
    if (s == 1 || (s & 7) == 7) FLUSH_REFRESH;
  }

  __syncthreads();                 // all waves' smin final
#pragma unroll
  for (int r = 0; r < 4; ++r) thr[r] = decf(smin[rbase + r]) + wlr[r];
  STEPBODY(0, 1);
  STEPBODY(1, 1);

  __syncthreads();
  const unsigned n = (lcnt < LLIST_CAP) ? lcnt : LLIST_CAP;
  if (tid == 0) gbase = (unsigned)atomicAdd(cand_n, (int)n);
  __syncthreads();
  for (unsigned i = tid; i < n; i += 256) {
    const unsigned g = gbase + i;
    if (g < CAND_CAP) cand[g] = llist[i];
  }

  // ---- one-hot zero-fill burst (end of kernel; no load-wait pollution) ----
  {
    const vf4 zz = {0.0f, 0.0f, 0.0f, 0.0f};
    float* zp0 = ohbase + 2;
    size_t zt = (size_t)b * 32768 + tid;
#pragma unroll 4
    for (int i = 0; i < 128; ++i) {
      if (zt < OH_VEC) __builtin_nontemporal_store(zz, (vf4*)(zp0 + 4 * zt));
      zt += 256;
    }
    if (b == 0 && tid == 0) { ohbase[0] = 0.0f; ohbase[1] = 0.0f; }
    if (b == 1023 && tid == 0) { ohbase[OH_TOT - 2] = 0.0f; ohbase[OH_TOT - 1] = 0.0f; }
  }
}

// ---------------------------------------------------------------------------
// k_recheck: exact fp32 chain (ascending-k fmaf, identical rounding to the
// reference) per candidate; u64-packed atomicMin -> exact argmin with
// np.argmin first-index tie-break.
// ---------------------------------------------------------------------------
__global__ __launch_bounds__(256) void k_recheck(
    const float* __restrict__ z, const float* __restrict__ emb,
    const float* __restrict__ zsq, const float* __restrict__ esq,
    const unsigned* __restrict__ cand, const int* __restrict__ cand_n,
    u64* __restrict__ best)
{
  const int n = min(*cand_n, CAND_CAP);
  for (int i = blockIdx.x * 256 + threadIdx.x; i < n; i += gridDim.x * 256) {
    const unsigned e = cand[i];
    const int row = (int)(e >> 13);
    const int col = (int)(e & (NE - 1));
    const float4* zr = (const float4*)(z + (size_t)row * DD);
    const float4* er = (const float4*)(emb + (size_t)col * DD);
    float dot = 0.0f;
#pragma unroll 8
    for (int q = 0; q < 64; ++q) {
      const float4 a = zr[q];
      const float4 b = er[q];
      dot = fmaf(a.x, b.x, dot);
      dot = fmaf(a.y, b.y, dot);
      dot = fmaf(a.z, b.z, dot);
      dot = fmaf(a.w, b.w, dot);
    }
    const float s1 = zsq[row] + esq[col];
    const float dv = s1 - 2.0f * dot;
    atomicMin(&best[row], ((u64)__float_as_uint(dv) << 32) | (unsigned)col);
  }
}

// ---------------------------------------------------------------------------
// k_gather2: 4 rows per block. z_q gather, one-hot 1.0 scatter (zeros laid
// down by k_screen's burst), float(index), counts, per-block loss partial.
// ---------------------------------------------------------------------------
__global__ __launch_bounds__(256) void k_gather2(
    const float* __restrict__ z, const float* __restrict__ emb,
    const u64* __restrict__ best,
    float* __restrict__ out_zq, float* __restrict__ out_onehot,
    float* __restrict__ out_idx, float* __restrict__ partials,
    int* __restrict__ counts)
{
  __shared__ float sred[256];
  const int row = blockIdx.x * 4 + (threadIdx.x >> 6);
  const int lane = threadIdx.x & 63;
  const int idx = (int)(unsigned)(best[row] & 0xffffffffull);
  const int k0 = lane * 4;

  const float4 e  = *(const float4*)(emb + (size_t)idx * DD + k0);
  const float4 zv = *(const float4*)(z + (size_t)row * DD + k0);
  *(float4*)(out_zq + (size_t)row * DD + k0) = e;

  const float dx = e.x - zv.x, dy = e.y - zv.y, dz = e.z - zv.z, dw = e.w - zv.w;
  sred[threadIdx.x] = dx * dx + dy * dy + dz * dz + dw * dw;

  if (lane == 0) {
    out_idx[row] = (float)idx;
    out_onehot[(size_t)row * NE + idx] = 1.0f;
    atomicAdd(&counts[idx], 1);
  }
  __syncthreads();
  for (int s = 128; s > 0; s >>= 1) {
    if (threadIdx.x < s) sred[threadIdx.x] += sred[threadIdx.x + s];
    __syncthreads();
  }
  if (threadIdx.x == 0) partials[blockIdx.x] = sred[0];
}

// ---------------------------------------------------------------------------
// k_final: loss = 1.25 * sum(partials) / (N*D); perplexity from counts.
// ---------------------------------------------------------------------------
__global__ __launch_bounds__(256) void k_final(
    const int* __restrict__ counts, const float* __restrict__ partials,
    float* __restrict__ out_loss, float* __restrict__ out_perp)
{
  __shared__ float sred[256];
  __shared__ float sl[256];
  float le = 0.0f;
  for (int e = threadIdx.x; e < NE; e += 256) {
    const float p = (float)counts[e] * (1.0f / 16384.0f);
    le += p * logf(p + 1e-10f);
  }
  float ll = 0.0f;
  for (int b = threadIdx.x; b < NROWS / 4; b += 256) ll += partials[b];
  sred[threadIdx.x] = le;
  sl[threadIdx.x] = ll;
  __syncthreads();
  for (int s = 128; s > 0; s >>= 1) {
    if (threadIdx.x < s) {
      sred[threadIdx.x] += sred[threadIdx.x + s];
      sl[threadIdx.x] += sl[threadIdx.x + s];
    }
    __syncthreads();
  }
  if (threadIdx.x == 0) {
    *out_perp = expf(-sred[0]);
    *out_loss = sl[0] * (1.25f / 4194304.0f);  // (1+beta) * sum / (N*D)
  }
}

// ---------------------------------------------------------------------------
// Output layout (float32, reference return order):
//   [0] loss | [1..4194304] z_q_st | [4194305] perplexity
//   [4194306..] one-hot | [138412034..] indices (as float)
// Workspace (floats): zsq 16K | esq 8K | best 32K | counts 8K | partials 4K |
//   wadd 16K | cand_n+pad | ebf (bf16 fragment-major, 1M floats) | cand 16MB
// (bulk intermediates live in d_ws -- d_out reads are uncached/slow.)
// ---------------------------------------------------------------------------
extern "C" void kernel_launch(void* const* d_in, const int* in_sizes, int n_in,
                              void* d_out, int out_size, void* d_ws, size_t ws_size,
                              hipStream_t stream) {
  const float* z   = (const float*)d_in[0];
  const float* emb = (const float*)d_in[1];

  float* out        = (float*)d_out;
  float* out_loss   = out;
  float* out_zq     = out + 1;
  float* out_perp   = out + 4194305;
  float* out_onehot = out + 4194306;
  float* out_idx    = out + 138412034;

  float* zsq      = (float*)d_ws;            // 16384 f
  float* esq      = zsq + NROWS;             // 8192 f
  u64*   best     = (u64*)(esq + NE);        // 16384 u64
  int*   counts   = (int*)(best + NROWS);    // 8192 int
  float* partials = (float*)(counts + NE);   // 4096 f
  float* wadd     = partials + 4096;         // 16384 f
  int*   cand_n   = (int*)(wadd + NROWS);    // 1 int (+pad to 16B)
  unsigned short* ebf = (unsigned short*)(wadd + NROWS + 4); // 8192*256 bf16
  unsigned* cand  = (unsigned*)(ebf + (size_t)NE * DD);      // 4M u32

  k_rowsq<<<96, 256, 0, stream>>>(z, emb, zsq, esq, best, counts, wadd, cand_n, ebf);
  k_screen<<<1024, 256, 0, stream>>>(z, ebf, esq, wadd, cand, cand_n, out_onehot);
  k_recheck<<<512, 256, 0, stream>>>(z, emb, zsq, esq, cand, cand_n, best);
  k_gather2<<<NROWS / 4, 256, 0, stream>>>(z, emb, best, out_zq, out_onehot,
                                           out_idx, partials, counts);
  k_final<<<1, 256, 0, stream>>>(counts, partials, out_loss, out_perp);
}